// Round 15
// baseline (56.743 us; speedup 1.0000x reference)
//
#include <hip/hip_runtime.h>
#include <hip/hip_bf16.h>
#include <math.h>

#define HW   4096
#define NC   64
#define NB   2
#define NHD  4
#define DH   16
#define NBH  (NB*NHD)

typedef __attribute__((ext_vector_type(4))) float f32x4;
typedef __attribute__((ext_vector_type(8))) short bf16x8;
typedef __attribute__((ext_vector_type(2))) unsigned int uint2v;

#define QSCALE 0.36067376022224087f   // 0.25 * log2(e)

static __device__ __forceinline__ unsigned short bf16_bits(float f) {
    union { __hip_bfloat16 h; unsigned short u; } cv;
    cv.h = __float2bfloat16(f);
    return cv.u;
}
static __device__ __forceinline__ float bits_to_f(unsigned short b) {
    return __uint_as_float(((unsigned int)b) << 16);
}
static __device__ __forceinline__ unsigned int cvt_pk_bf16(float lo, float hi) {
    unsigned int r;
    asm("v_cvt_pk_bf16_f32 %0, %1, %2" : "=v"(r) : "v"(lo), "v"(hi));
    return r;
}

// ---------------------------------------------------------------------------
// Kernel W: weight prep for qkv AND proj MFMA GEMMs (round-14 verbatim).
// ---------------------------------------------------------------------------
__global__ __launch_bounds__(256) void wprep_kernel(
    const float* __restrict__ qkv_w, const float* __restrict__ qkv_b,
    const float* __restrict__ illu_w, const float* __restrict__ illu_b,
    const float* __restrict__ proj_w,
    ushort* __restrict__ Wt, float* __restrict__ Bias, ushort* __restrict__ Wp)
{
    int idx = blockIdx.x * 256 + threadIdx.x;
    if (idx < 49152) {
        int k8 = idx & 15;
        int n  = (idx >> 4) & 15;
        int hl = (idx >> 8) & 1;
        int ct = (idx >> 9) & 7;
        int ot = idx >> 12;              // 0..11
        int c   = ct*16 + k8;            // 0..127
        int out = ot*16 + n;             // 0..191
        float w;
        if (ot < 4)       w = (c < 64) ? qkv_w[out*64 + c] * QSCALE : 0.f;
        else if (ot < 8)  w = (c < 64) ? qkv_w[out*64 + c]
                                       : illu_w[(out-64)*64 + (c-64)];
        else              w = (c < 64) ? qkv_w[out*64 + c] : 0.f;
        unsigned short hb = bf16_bits(w);
        Wt[idx] = (hl == 0) ? hb : bf16_bits(w - bits_to_f(hb));
    } else if (idx < 49344) {
        int out = idx - 49152;
        float bv = (out < 64)  ? qkv_b[out] * QSCALE
                 : (out < 128) ? qkv_b[out] + illu_b[out-64]
                 :               qkv_b[out];
        Bias[out] = bv;
    } else if (idx < 49344 + 8192) {
        int local = idx - 49344;
        int k8 = local & 15;
        int n  = (local >> 4) & 15;
        int hl = (local >> 8) & 1;
        int ct = (local >> 9) & 3;
        int ot = local >> 11;            // 0..3
        float w = proj_w[(ot*16 + n)*64 + ct*16 + k8];
        unsigned short hb = bf16_bits(w);
        Wp[local] = (hl == 0) ? hb : bf16_bits(w - bits_to_f(hb));
    }
}

// ---------------------------------------------------------------------------
// Kernel A: qkv+illu as double-bf16 MFMA GEMM (round-13/14 verbatim).
// ---------------------------------------------------------------------------
__global__ __launch_bounds__(256) void qkv_kernel(
    const float* __restrict__ x, const float* __restrict__ illu,
    const ushort* __restrict__ Wt, const float* __restrict__ Bias,
    ushort* __restrict__ Qx, ushort* __restrict__ Kx, ushort* __restrict__ Vt)
{
    __shared__ alignas(16) float  xf[128*20];    // [z-row 128][16 px + 4 pad]
    __shared__ alignas(16) ushort frag[8*16*32]; // [ct][px][32 slots swz]

    int blk = blockIdx.x;                // 512
    int b   = blk & 1;
    int px0 = (blk >> 1) * 16;
    int tid = threadIdx.x;
    int w   = tid >> 6;
    int lane = tid & 63;
    int g   = lane >> 4;
    int n   = lane & 15;

    #pragma unroll
    for (int rep = 0; rep < 2; ++rep) {
        int id  = tid + rep*256;
        int row = id >> 2, seg = id & 3;
        const float* src = (row < 64) ? x    + (size_t)(b*NC + row)*HW
                                      : illu + (size_t)(b*NC + row - 64)*HW;
        float4 v = *(const float4*)(src + px0 + seg*4);
        *(float4*)(xf + row*20 + seg*4) = v;
    }
    __syncthreads();

    if (tid < 128) {
        int ct = tid >> 4, px = tid & 15;
        int swz = (px & 3) ^ ((px >> 2) & 3);
        union { ushort us[8]; bf16x8 v; } g0, g1, g2, g3;
        #pragma unroll
        for (int i = 0; i < 8; ++i) {
            float v  = xf[(ct*16 + i)*20 + px];
            unsigned short hb = bf16_bits(v);
            g0.us[i] = hb;
            g2.us[i] = bf16_bits(v - bits_to_f(hb));
            float v2 = xf[(ct*16 + 8 + i)*20 + px];
            unsigned short hb2 = bf16_bits(v2);
            g1.us[i] = hb2;
            g3.us[i] = bf16_bits(v2 - bits_to_f(hb2));
        }
        ushort* fb = frag + (ct*16 + px)*32;
        *(bf16x8*)(fb + ((0 ^ swz)*8)) = g0.v;
        *(bf16x8*)(fb + ((1 ^ swz)*8)) = g1.v;
        *(bf16x8*)(fb + ((2 ^ swz)*8)) = g2.v;
        *(bf16x8*)(fb + ((3 ^ swz)*8)) = g3.v;
    }
    __syncthreads();

    f32x4 zero4 = {0.f, 0.f, 0.f, 0.f};
    int px  = n;
    int swz = (px & 3) ^ ((px >> 2) & 3);
    const ushort* af_base = frag + px*32 + (g ^ swz)*8;

    #pragma unroll
    for (int j = 0; j < 3; ++j) {
        int ot  = w + 4*j;                // 0..11
        int nct = (ot >= 4 && ot < 8) ? 8 : 4;
        f32x4 acc = zero4;
        for (int ct = 0; ct < nct; ++ct) {
            bf16x8 af = *(const bf16x8*)(af_base + ct*512);
            const ushort* wb = Wt + ((size_t)(ot*8 + ct)*2)*256 + n*16 + (g&1)*8;
            bf16x8 bh = *(const bf16x8*)(wb);
            bf16x8 bl = *(const bf16x8*)(wb + 256);
            acc = __builtin_amdgcn_mfma_f32_16x16x32_bf16(af, bh, acc, 0, 0, 0);
            acc = __builtin_amdgcn_mfma_f32_16x16x32_bf16(af, bl, acc, 0, 0, 0);
        }
        float bias = Bias[ot*16 + n];
        float v0 = acc.x + bias, v1 = acc.y + bias;
        float v2 = acc.z + bias, v3 = acc.w + bias;
        if (ot < 8) {
            ushort* dst = (ot < 4) ? Qx : Kx;
            int head = ot & 3;
            size_t base = ((size_t)(b*NHD + head))*HW*32;
            #pragma unroll
            for (int r = 0; r < 4; ++r) {
                float val = (r==0? v0 : r==1? v1 : r==2? v2 : v3);
                int pxr = px0 + 4*g + r;
                unsigned short hb = bf16_bits(val);
                dst[base + (size_t)pxr*32 + n]      = hb;
                dst[base + (size_t)pxr*32 + 16 + n] = bf16_bits(val - bits_to_f(hb));
            }
        } else {
            int co = (ot - 8)*16 + n;
            uint2v pk;
            pk.x = cvt_pk_bf16(v0, v1);
            pk.y = cvt_pk_bf16(v2, v3);
            *(uint2v*)(Vt + ((size_t)(b*NC + co))*HW + px0 + 4*g) = pk;
        }
    }
}

// ---------------------------------------------------------------------------
// Kernel B: MFMA flash attention. Round-13 structure with two deletions:
// (1) l computed by ones-MFMA (oaccL = mfma(P, ones)) on the matrix pipe --
//     removes 32 VALU adds/tile/wave and all shuffles; l now from the SAME
//     bf16 P as the numerator (consistent ratio).
// (2) V read directly from L2-resident Vt (XCD-affine bh => 128KB/XCD L2);
//     Vs LDS + V staging deleted. V values bit-identical.
// 4-way split-K, 1 wave/split, 2 q-tiles/wave, KT=64, depth-2 K prefetch.
// LDS = 32KB (Ks only; merge reuses it).
// ---------------------------------------------------------------------------
#define KT   64
#define SPL  4
#define KPS  1024
#define NTS  (KPS/KT)

__global__ __launch_bounds__(512) void attn_kernel(
    const ushort* __restrict__ Qx, const ushort* __restrict__ Kx,
    const ushort* __restrict__ Vt, float* __restrict__ O)
{
    __shared__ alignas(16) ushort Ks[SPL][2][64*32];  // 32KB [split][buf]

    int blk  = blockIdx.x;               // 512
    int bh   = blk & 7;                  // XCD-affine
    int q0   = (blk >> 3) * 64;
    int tid  = threadIdx.x;
    int w    = tid >> 6;
    int s    = w >> 1;                   // split 0..3
    int u    = w & 1;                    // q-tiles 2u, 2u+1
    int lane = tid & 63;
    int g    = lane >> 4;
    int qc   = lane & 15;

    const ushort* Qb = Qx + (size_t)bh*HW*32;
    const ushort* Kb = Kx + (size_t)bh*HW*32 + (size_t)s*KPS*32;
    const ushort* Vb = Vt + (size_t)bh*DH*HW;

    int qrow0 = q0 + (u*2 + 0)*16 + qc;
    int qrow1 = q0 + (u*2 + 1)*16 + qc;
    bf16x8 qhi0 = *(const bf16x8*)(Qb + (size_t)qrow0*32 +      8*(g&1));
    bf16x8 qlo0 = *(const bf16x8*)(Qb + (size_t)qrow0*32 + 16 + 8*(g&1));
    bf16x8 qhi1 = *(const bf16x8*)(Qb + (size_t)qrow1*32 +      8*(g&1));
    bf16x8 qlo1 = *(const bf16x8*)(Qb + (size_t)qrow1*32 + 16 + 8*(g&1));

    f32x4 zero4 = {0.f, 0.f, 0.f, 0.f};
    f32x4 oacc0 = zero4, oacc1 = zero4;
    f32x4 oaccL0 = zero4, oaccL1 = zero4;   // denominators via ones-MFMA

    union { unsigned int uu[4]; bf16x8 h; } ones;
    ones.uu[0] = 0x3F803F80u; ones.uu[1] = 0x3F803F80u;
    ones.uu[2] = 0x3F803F80u; ones.uu[3] = 0x3F803F80u;

    int mconst = (qc & 3) ^ ((qc >> 2) & 3);
    const int koff = qc*32 + ((g ^ mconst)*8);
    // per-lane V global base: row d=qc of this split's keys, col 4g
    const ushort* vbase = Vb + (size_t)qc*HW + s*KPS + 4*g;

    // K staging: 128 thr per split stage 256 x 16B chunks (2 each)
    int gt = tid & 127;
    int f0 = gt,        r0 = f0 >> 2, h0 = f0 & 3;
    int f1 = gt + 128,  r1 = f1 >> 2, h1 = f1 & 3;
    int s0 = (h0 ^ ((r0 & 3) ^ ((r0 >> 2) & 3))) * 8;
    int s1 = (h1 ^ ((r1 & 3) ^ ((r1 >> 2) & 3))) * 8;

    // prologue: tile 0 -> buf0; tile 1 in-flight
    {
        bf16x8 a0 = *(const bf16x8*)(Kb + (size_t)r0*32 + 8*h0);
        bf16x8 a1 = *(const bf16x8*)(Kb + (size_t)r1*32 + 8*h1);
        *(bf16x8*)(&Ks[s][0][0] + r0*32 + s0) = a0;
        *(bf16x8*)(&Ks[s][0][0] + r1*32 + s1) = a1;
    }
    bf16x8 k0b = *(const bf16x8*)(Kb + (size_t)(KT + r0)*32 + 8*h0);
    bf16x8 k1b = *(const bf16x8*)(Kb + (size_t)(KT + r1)*32 + 8*h1);

    for (int t = 0; t < NTS; ++t) {
        __syncthreads();
        bf16x8 k0c = k0b, k1c = k1b;
        if (t + 2 < NTS) {               // issue K loads for tile t+2
            int kt = (t + 2) * KT;
            k0c = *(const bf16x8*)(Kb + (size_t)(kt + r0)*32 + 8*h0);
            k1c = *(const bf16x8*)(Kb + (size_t)(kt + r1)*32 + 8*h1);
        }

        const ushort* kr = &Ks[s][t & 1][0] + koff;
        const ushort* vt = vbase + t*KT;
        unsigned int pe00 = 0, pe01 = 0, pe10 = 0, pe11 = 0;
        #pragma unroll
        for (int kb = 0; kb < 4; ++kb) {
            bf16x8 kfrag = *(const bf16x8*)(kr + kb*512);
            // q-tile 0
            f32x4 sA = __builtin_amdgcn_mfma_f32_16x16x32_bf16(kfrag, qhi0, zero4, 0, 0, 0);
            sA = __builtin_amdgcn_mfma_f32_16x16x32_bf16(kfrag, qlo0, sA, 0, 0, 0);
            float a0 = __builtin_amdgcn_exp2f(sA.x);
            float a1 = __builtin_amdgcn_exp2f(sA.y);
            float a2 = __builtin_amdgcn_exp2f(sA.z);
            float a3 = __builtin_amdgcn_exp2f(sA.w);
            unsigned int alo = cvt_pk_bf16(a0, a1);
            unsigned int ahi = cvt_pk_bf16(a2, a3);
            // q-tile 1
            f32x4 sB = __builtin_amdgcn_mfma_f32_16x16x32_bf16(kfrag, qhi1, zero4, 0, 0, 0);
            sB = __builtin_amdgcn_mfma_f32_16x16x32_bf16(kfrag, qlo1, sB, 0, 0, 0);
            float b0 = __builtin_amdgcn_exp2f(sB.x);
            float b1 = __builtin_amdgcn_exp2f(sB.y);
            float b2 = __builtin_amdgcn_exp2f(sB.z);
            float b3 = __builtin_amdgcn_exp2f(sB.w);
            unsigned int blo = cvt_pk_bf16(b0, b1);
            unsigned int bhi = cvt_pk_bf16(b2, b3);

            if ((kb & 1) == 0) { pe00 = alo; pe01 = ahi; pe10 = blo; pe11 = bhi; }
            else {
                uint2v vE = *(const uint2v*)(vt + (kb-1)*16);   // global (L2)
                uint2v vO = *(const uint2v*)(vt + kb*16);
                union { unsigned int uu[4]; bf16x8 h; } pa, vv;
                vv.uu[0] = vE.x; vv.uu[1] = vE.y; vv.uu[2] = vO.x; vv.uu[3] = vO.y;
                pa.uu[0] = pe00; pa.uu[1] = pe01; pa.uu[2] = alo; pa.uu[3] = ahi;
                oacc0  = __builtin_amdgcn_mfma_f32_16x16x32_bf16(pa.h, vv.h,   oacc0,  0, 0, 0);
                oaccL0 = __builtin_amdgcn_mfma_f32_16x16x32_bf16(pa.h, ones.h, oaccL0, 0, 0, 0);
                pa.uu[0] = pe10; pa.uu[1] = pe11; pa.uu[2] = blo; pa.uu[3] = bhi;
                oacc1  = __builtin_amdgcn_mfma_f32_16x16x32_bf16(pa.h, vv.h,   oacc1,  0, 0, 0);
                oaccL1 = __builtin_amdgcn_mfma_f32_16x16x32_bf16(pa.h, ones.h, oaccL1, 0, 0, 0);
            }
        }

        if (t + 1 < NTS) {               // write in-flight K tile -> other buf
            int nb = (t + 1) & 1;
            *(bf16x8*)(&Ks[s][nb][0] + r0*32 + s0) = k0b;
            *(bf16x8*)(&Ks[s][nb][0] + r1*32 + s1) = k1b;
            k0b = k0c; k1b = k1c;
        }
    }

    // merge splits 1..3 -> split 0, reusing Ks LDS (staging dead now)
    // entry per (split-1, u, qtile, lane): 8 floats = oacc.xyzw | oaccL.xyzw
    __syncthreads();
    float* mrgF = (float*)&Ks[0][0][0];   // [3][2][2][64][8] = 24KB
    if (s > 0) {
        float* m0 = mrgF + (((((s-1)*2 + u)*2 + 0)*64 + lane)*8);
        m0[0] = oacc0.x;  m0[1] = oacc0.y;  m0[2] = oacc0.z;  m0[3] = oacc0.w;
        m0[4] = oaccL0.x; m0[5] = oaccL0.y; m0[6] = oaccL0.z; m0[7] = oaccL0.w;
        float* m1 = mrgF + (((((s-1)*2 + u)*2 + 1)*64 + lane)*8);
        m1[0] = oacc1.x;  m1[1] = oacc1.y;  m1[2] = oacc1.z;  m1[3] = oacc1.w;
        m1[4] = oaccL1.x; m1[5] = oaccL1.y; m1[6] = oaccL1.z; m1[7] = oaccL1.w;
    }
    __syncthreads();
    if (s == 0) {
        #pragma unroll
        for (int sp = 0; sp < 3; ++sp) {
            const float* m0 = mrgF + ((((sp*2 + u)*2 + 0)*64 + lane)*8);
            oacc0.x  += m0[0]; oacc0.y  += m0[1]; oacc0.z  += m0[2]; oacc0.w  += m0[3];
            oaccL0.x += m0[4]; oaccL0.y += m0[5]; oaccL0.z += m0[6]; oaccL0.w += m0[7];
            const float* m1 = mrgF + ((((sp*2 + u)*2 + 1)*64 + lane)*8);
            oacc1.x  += m1[0]; oacc1.y  += m1[1]; oacc1.z  += m1[2]; oacc1.w  += m1[3];
            oaccL1.x += m1[4]; oaccL1.y += m1[5]; oaccL1.z += m1[6]; oaccL1.w += m1[7];
        }
        int b = bh >> 2, h = bh & 3;
        float* Ob0 = O + ((size_t)b*HW + q0 + (u*2 + 0)*16)*NC + h*DH;
        float* Ob1 = O + ((size_t)b*HW + q0 + (u*2 + 1)*16)*NC + h*DH;
        #pragma unroll
        for (int r = 0; r < 4; ++r) {
            float ov0 = (r==0? oacc0.x  : r==1? oacc0.y  : r==2? oacc0.z  : oacc0.w);
            float lv0 = (r==0? oaccL0.x : r==1? oaccL0.y : r==2? oaccL0.z : oaccL0.w);
            Ob0[(4*g + r)*NC + qc] = ov0 / lv0;
            float ov1 = (r==0? oacc1.x  : r==1? oacc1.y  : r==2? oacc1.z  : oacc1.w);
            float lv1 = (r==0? oaccL1.x : r==1? oaccL1.y : r==2? oaccL1.z : oaccL1.w);
            Ob1[(4*g + r)*NC + qc] = ov1 / lv1;
        }
    }
}

// ---------------------------------------------------------------------------
// Kernel C: proj as double-bf16 MFMA GEMM (round-14 verbatim).
// ---------------------------------------------------------------------------
__global__ __launch_bounds__(256) void proj_kernel(
    const float* __restrict__ O, const ushort* __restrict__ Wp,
    const float* __restrict__ proj_b, float* __restrict__ y)
{
    __shared__ alignas(16) float  of[64*20];     // [c][16 px + 4 pad]
    __shared__ alignas(16) ushort frag[4*16*32]; // [ct][px][32 swz]
    __shared__ alignas(16) float  ys[64][20];    // [c][px]

    int blk = blockIdx.x;                // 512
    int b   = blk & 1;
    int px0 = (blk >> 1) * 16;
    int tid = threadIdx.x;
    int w   = tid >> 6;
    int lane = tid & 63;
    int g   = lane >> 4;
    int n   = lane & 15;

    {
        int px = tid >> 4, c4 = tid & 15;
        float4 v = *(const float4*)(O + ((size_t)(b*HW + px0 + px))*NC + c4*4);
        of[(c4*4+0)*20 + px] = v.x;
        of[(c4*4+1)*20 + px] = v.y;
        of[(c4*4+2)*20 + px] = v.z;
        of[(c4*4+3)*20 + px] = v.w;
    }
    __syncthreads();

    if (tid < 64) {
        int ct = tid >> 4, px = tid & 15;
        int swz = (px & 3) ^ ((px >> 2) & 3);
        union { ushort us[8]; bf16x8 v; } g0, g1, g2, g3;
        #pragma unroll
        for (int i = 0; i < 8; ++i) {
            float v  = of[(ct*16 + i)*20 + px];
            unsigned short hb = bf16_bits(v);
            g0.us[i] = hb;
            g2.us[i] = bf16_bits(v - bits_to_f(hb));
            float v2 = of[(ct*16 + 8 + i)*20 + px];
            unsigned short hb2 = bf16_bits(v2);
            g1.us[i] = hb2;
            g3.us[i] = bf16_bits(v2 - bits_to_f(hb2));
        }
        ushort* fb = frag + (ct*16 + px)*32;
        *(bf16x8*)(fb + ((0 ^ swz)*8)) = g0.v;
        *(bf16x8*)(fb + ((1 ^ swz)*8)) = g1.v;
        *(bf16x8*)(fb + ((2 ^ swz)*8)) = g2.v;
        *(bf16x8*)(fb + ((3 ^ swz)*8)) = g3.v;
    }
    __syncthreads();

    f32x4 acc = {0.f, 0.f, 0.f, 0.f};
    int px  = n;
    int swz = (px & 3) ^ ((px >> 2) & 3);
    const ushort* af_base = frag + px*32 + (g ^ swz)*8;
    #pragma unroll
    for (int ct = 0; ct < 4; ++ct) {
        bf16x8 af = *(const bf16x8*)(af_base + ct*512);
        const ushort* wb = Wp + ((size_t)(w*4 + ct)*2)*256 + n*16 + (g&1)*8;
        bf16x8 bh = *(const bf16x8*)(wb);
        bf16x8 bl = *(const bf16x8*)(wb + 256);
        acc = __builtin_amdgcn_mfma_f32_16x16x32_bf16(af, bh, acc, 0, 0, 0);
        acc = __builtin_amdgcn_mfma_f32_16x16x32_bf16(af, bl, acc, 0, 0, 0);
    }
    float bias = proj_b[w*16 + n];
    ys[w*16 + n][4*g+0] = acc.x + bias;
    ys[w*16 + n][4*g+1] = acc.y + bias;
    ys[w*16 + n][4*g+2] = acc.z + bias;
    ys[w*16 + n][4*g+3] = acc.w + bias;
    __syncthreads();

    {
        int row = tid >> 2, seg = tid & 3;
        float4 v;
        v.x = ys[row][seg*4+0]; v.y = ys[row][seg*4+1];
        v.z = ys[row][seg*4+2]; v.w = ys[row][seg*4+3];
        *(float4*)(y + ((size_t)(b*NC + row))*HW + px0 + seg*4) = v;
    }
}

// ---------------------------------------------------------------------------
extern "C" void kernel_launch(void* const* d_in, const int* in_sizes, int n_in,
                              void* d_out, int out_size, void* d_ws, size_t ws_size,
                              hipStream_t stream)
{
    const float* x      = (const float*)d_in[0];
    const float* illu   = (const float*)d_in[1];
    const float* qkv_w  = (const float*)d_in[2];
    const float* qkv_b  = (const float*)d_in[3];
    const float* illu_w = (const float*)d_in[4];
    const float* illu_b = (const float*)d_in[5];
    const float* proj_w = (const float*)d_in[6];
    const float* proj_b = (const float*)d_in[7];
    float* out = (float*)d_out;

    ushort* Qx   = (ushort*)d_ws;                     // 2MB (hi|lo)
    ushort* Kx   = Qx + (size_t)NBH*HW*32;            // 2MB (hi|lo)
    ushort* Vt   = Kx + (size_t)NBH*HW*32;            // 1MB [bh][d][key]
    float*  O    = (float*)(Vt + (size_t)NBH*HW*DH);  // 2MB fp32 [b][p][64]
    ushort* Wt   = (ushort*)(O + (size_t)NB*HW*NC);   // 96KB
    float*  Bias = (float*)(Wt + 49152);              // 768B
    ushort* Wp   = (ushort*)(Bias + 192);             // 16KB

    hipLaunchKernelGGL(wprep_kernel, dim3(225), dim3(256), 0, stream,
                       qkv_w, qkv_b, illu_w, illu_b, proj_w, Wt, Bias, Wp);
    hipLaunchKernelGGL(qkv_kernel, dim3(512), dim3(256), 0, stream,
                       x, illu, Wt, Bias, Qx, Kx, Vt);
    hipLaunchKernelGGL(attn_kernel, dim3(512), dim3(512), 0, stream,
                       Qx, Kx, Vt, O);
    hipLaunchKernelGGL(proj_kernel, dim3(512), dim3(256), 0, stream,
                       O, Wp, proj_b, out);
}

// Round 16
// 46.819 us; speedup vs baseline: 1.2120x; 1.2120x over previous
//
#include <hip/hip_runtime.h>
#include <hip/hip_bf16.h>
#include <math.h>

#define HW   4096
#define NC   64
#define NB   2
#define NHD  4
#define DH   16
#define NBH  (NB*NHD)

typedef __attribute__((ext_vector_type(4))) float f32x4;
typedef __attribute__((ext_vector_type(8))) short bf16x8;
typedef __attribute__((ext_vector_type(2))) unsigned int uint2v;

#define QSCALE 0.36067376022224087f   // 0.25 * log2(e)

static __device__ __forceinline__ unsigned short bf16_bits(float f) {
    union { __hip_bfloat16 h; unsigned short u; } cv;
    cv.h = __float2bfloat16(f);
    return cv.u;
}
static __device__ __forceinline__ float bits_to_f(unsigned short b) {
    return __uint_as_float(((unsigned int)b) << 16);
}
static __device__ __forceinline__ unsigned int cvt_pk_bf16(float lo, float hi) {
    unsigned int r;
    asm("v_cvt_pk_bf16_f32 %0, %1, %2" : "=v"(r) : "v"(lo), "v"(hi));
    return r;
}

// ---------------------------------------------------------------------------
// Kernel W: weight prep for qkv AND proj MFMA GEMMs (round-14 verbatim).
// ---------------------------------------------------------------------------
__global__ __launch_bounds__(256) void wprep_kernel(
    const float* __restrict__ qkv_w, const float* __restrict__ qkv_b,
    const float* __restrict__ illu_w, const float* __restrict__ illu_b,
    const float* __restrict__ proj_w,
    ushort* __restrict__ Wt, float* __restrict__ Bias, ushort* __restrict__ Wp)
{
    int idx = blockIdx.x * 256 + threadIdx.x;
    if (idx < 49152) {
        int k8 = idx & 15;
        int n  = (idx >> 4) & 15;
        int hl = (idx >> 8) & 1;
        int ct = (idx >> 9) & 7;
        int ot = idx >> 12;              // 0..11
        int c   = ct*16 + k8;            // 0..127
        int out = ot*16 + n;             // 0..191
        float w;
        if (ot < 4)       w = (c < 64) ? qkv_w[out*64 + c] * QSCALE : 0.f;
        else if (ot < 8)  w = (c < 64) ? qkv_w[out*64 + c]
                                       : illu_w[(out-64)*64 + (c-64)];
        else              w = (c < 64) ? qkv_w[out*64 + c] : 0.f;
        unsigned short hb = bf16_bits(w);
        Wt[idx] = (hl == 0) ? hb : bf16_bits(w - bits_to_f(hb));
    } else if (idx < 49344) {
        int out = idx - 49152;
        float bv = (out < 64)  ? qkv_b[out] * QSCALE
                 : (out < 128) ? qkv_b[out] + illu_b[out-64]
                 :               qkv_b[out];
        Bias[out] = bv;
    } else if (idx < 49344 + 8192) {
        int local = idx - 49344;
        int k8 = local & 15;
        int n  = (local >> 4) & 15;
        int hl = (local >> 8) & 1;
        int ct = (local >> 9) & 3;
        int ot = local >> 11;            // 0..3
        float w = proj_w[(ot*16 + n)*64 + ct*16 + k8];
        unsigned short hb = bf16_bits(w);
        Wp[local] = (hl == 0) ? hb : bf16_bits(w - bits_to_f(hb));
    }
}

// ---------------------------------------------------------------------------
// Kernel A: qkv+illu as double-bf16 MFMA GEMM (round-13/14 verbatim).
// ---------------------------------------------------------------------------
__global__ __launch_bounds__(256) void qkv_kernel(
    const float* __restrict__ x, const float* __restrict__ illu,
    const ushort* __restrict__ Wt, const float* __restrict__ Bias,
    ushort* __restrict__ Qx, ushort* __restrict__ Kx, ushort* __restrict__ Vt)
{
    __shared__ alignas(16) float  xf[128*20];    // [z-row 128][16 px + 4 pad]
    __shared__ alignas(16) ushort frag[8*16*32]; // [ct][px][32 slots swz]

    int blk = blockIdx.x;                // 512
    int b   = blk & 1;
    int px0 = (blk >> 1) * 16;
    int tid = threadIdx.x;
    int w   = tid >> 6;
    int lane = tid & 63;
    int g   = lane >> 4;
    int n   = lane & 15;

    #pragma unroll
    for (int rep = 0; rep < 2; ++rep) {
        int id  = tid + rep*256;
        int row = id >> 2, seg = id & 3;
        const float* src = (row < 64) ? x    + (size_t)(b*NC + row)*HW
                                      : illu + (size_t)(b*NC + row - 64)*HW;
        float4 v = *(const float4*)(src + px0 + seg*4);
        *(float4*)(xf + row*20 + seg*4) = v;
    }
    __syncthreads();

    if (tid < 128) {
        int ct = tid >> 4, px = tid & 15;
        int swz = (px & 3) ^ ((px >> 2) & 3);
        union { ushort us[8]; bf16x8 v; } g0, g1, g2, g3;
        #pragma unroll
        for (int i = 0; i < 8; ++i) {
            float v  = xf[(ct*16 + i)*20 + px];
            unsigned short hb = bf16_bits(v);
            g0.us[i] = hb;
            g2.us[i] = bf16_bits(v - bits_to_f(hb));
            float v2 = xf[(ct*16 + 8 + i)*20 + px];
            unsigned short hb2 = bf16_bits(v2);
            g1.us[i] = hb2;
            g3.us[i] = bf16_bits(v2 - bits_to_f(hb2));
        }
        ushort* fb = frag + (ct*16 + px)*32;
        *(bf16x8*)(fb + ((0 ^ swz)*8)) = g0.v;
        *(bf16x8*)(fb + ((1 ^ swz)*8)) = g1.v;
        *(bf16x8*)(fb + ((2 ^ swz)*8)) = g2.v;
        *(bf16x8*)(fb + ((3 ^ swz)*8)) = g3.v;
    }
    __syncthreads();

    f32x4 zero4 = {0.f, 0.f, 0.f, 0.f};
    int px  = n;
    int swz = (px & 3) ^ ((px >> 2) & 3);
    const ushort* af_base = frag + px*32 + (g ^ swz)*8;

    #pragma unroll
    for (int j = 0; j < 3; ++j) {
        int ot  = w + 4*j;                // 0..11
        int nct = (ot >= 4 && ot < 8) ? 8 : 4;
        f32x4 acc = zero4;
        for (int ct = 0; ct < nct; ++ct) {
            bf16x8 af = *(const bf16x8*)(af_base + ct*512);
            const ushort* wb = Wt + ((size_t)(ot*8 + ct)*2)*256 + n*16 + (g&1)*8;
            bf16x8 bh = *(const bf16x8*)(wb);
            bf16x8 bl = *(const bf16x8*)(wb + 256);
            acc = __builtin_amdgcn_mfma_f32_16x16x32_bf16(af, bh, acc, 0, 0, 0);
            acc = __builtin_amdgcn_mfma_f32_16x16x32_bf16(af, bl, acc, 0, 0, 0);
        }
        float bias = Bias[ot*16 + n];
        float v0 = acc.x + bias, v1 = acc.y + bias;
        float v2 = acc.z + bias, v3 = acc.w + bias;
        if (ot < 8) {
            ushort* dst = (ot < 4) ? Qx : Kx;
            int head = ot & 3;
            size_t base = ((size_t)(b*NHD + head))*HW*32;
            #pragma unroll
            for (int r = 0; r < 4; ++r) {
                float val = (r==0? v0 : r==1? v1 : r==2? v2 : v3);
                int pxr = px0 + 4*g + r;
                unsigned short hb = bf16_bits(val);
                dst[base + (size_t)pxr*32 + n]      = hb;
                dst[base + (size_t)pxr*32 + 16 + n] = bf16_bits(val - bits_to_f(hb));
            }
        } else {
            int co = (ot - 8)*16 + n;
            uint2v pk;
            pk.x = cvt_pk_bf16(v0, v1);
            pk.y = cvt_pk_bf16(v2, v3);
            *(uint2v*)(Vt + ((size_t)(b*NC + co))*HW + px0 + 4*g) = pk;
        }
    }
}

// ---------------------------------------------------------------------------
// Kernel B: MFMA flash attention. Round-13/14 V-in-LDS structure
// + ones-MFMA denominator (l = mfma(P, ones) on the matrix pipe; no VALU
//   adds, no shuffles; l consistent with the numerator's bf16 P).
// 4-way split-K, 1 wave/split, 2 q-tiles/wave, KT=64, XCD-affine bh,
// depth-2 prefetch for K AND V. LDS = 50KB (Ks 32 + Vs 18; merge reuses Ks).
// ---------------------------------------------------------------------------
#define KT   64
#define SPL  4
#define KPS  1024
#define NTS  (KPS/KT)

__global__ __launch_bounds__(512) void attn_kernel(
    const ushort* __restrict__ Qx, const ushort* __restrict__ Kx,
    const ushort* __restrict__ Vt, float* __restrict__ O)
{
    __shared__ alignas(16) ushort Ks[SPL][2][64*32];  // 32KB [split][buf]
    __shared__ alignas(16) ushort Vs[SPL][2][16*72];  // 18KB [d][64+8pad]

    int blk  = blockIdx.x;               // 512
    int bh   = blk & 7;                  // XCD-affine
    int q0   = (blk >> 3) * 64;
    int tid  = threadIdx.x;
    int w    = tid >> 6;
    int s    = w >> 1;                   // split 0..3
    int u    = w & 1;                    // q-tiles 2u, 2u+1
    int lane = tid & 63;
    int g    = lane >> 4;
    int qc   = lane & 15;

    const ushort* Qb = Qx + (size_t)bh*HW*32;
    const ushort* Kb = Kx + (size_t)bh*HW*32 + (size_t)s*KPS*32;
    const ushort* Vb = Vt + (size_t)bh*DH*HW;

    int qrow0 = q0 + (u*2 + 0)*16 + qc;
    int qrow1 = q0 + (u*2 + 1)*16 + qc;
    bf16x8 qhi0 = *(const bf16x8*)(Qb + (size_t)qrow0*32 +      8*(g&1));
    bf16x8 qlo0 = *(const bf16x8*)(Qb + (size_t)qrow0*32 + 16 + 8*(g&1));
    bf16x8 qhi1 = *(const bf16x8*)(Qb + (size_t)qrow1*32 +      8*(g&1));
    bf16x8 qlo1 = *(const bf16x8*)(Qb + (size_t)qrow1*32 + 16 + 8*(g&1));

    f32x4 zero4 = {0.f, 0.f, 0.f, 0.f};
    f32x4 oacc0 = zero4, oacc1 = zero4;
    f32x4 oaccL0 = zero4, oaccL1 = zero4;   // denominators via ones-MFMA

    union { unsigned int uu[4]; bf16x8 h; } ones;
    ones.uu[0] = 0x3F803F80u; ones.uu[1] = 0x3F803F80u;
    ones.uu[2] = 0x3F803F80u; ones.uu[3] = 0x3F803F80u;

    int mconst = (qc & 3) ^ ((qc >> 2) & 3);
    const int koff = qc*32 + ((g ^ mconst)*8);
    const int voff = qc*72 + 4*g;

    // staging-side: 128 thr per split; K tile 256 chunks (2/thr), V 128 (1/thr)
    int gt = tid & 127;
    int f0 = gt,        r0 = f0 >> 2, h0 = f0 & 3;
    int f1 = gt + 128,  r1 = f1 >> 2, h1 = f1 & 3;
    int s0 = (h0 ^ ((r0 & 3) ^ ((r0 >> 2) & 3))) * 8;
    int s1 = (h1 ^ ((r1 & 3) ^ ((r1 >> 2) & 3))) * 8;
    int vd = gt >> 3, vseg = gt & 7;

    // prologue: tile 0 -> buf0; tile 1 in-flight
    {
        bf16x8 a0 = *(const bf16x8*)(Kb + (size_t)r0*32 + 8*h0);
        bf16x8 a1 = *(const bf16x8*)(Kb + (size_t)r1*32 + 8*h1);
        bf16x8 av = *(const bf16x8*)(Vb + (size_t)vd*HW + s*KPS + vseg*8);
        *(bf16x8*)(&Ks[s][0][0] + r0*32 + s0) = a0;
        *(bf16x8*)(&Ks[s][0][0] + r1*32 + s1) = a1;
        *(bf16x8*)(&Vs[s][0][0] + vd*72 + vseg*8) = av;
    }
    bf16x8 k0b = *(const bf16x8*)(Kb + (size_t)(KT + r0)*32 + 8*h0);
    bf16x8 k1b = *(const bf16x8*)(Kb + (size_t)(KT + r1)*32 + 8*h1);
    bf16x8 vb_ = *(const bf16x8*)(Vb + (size_t)vd*HW + s*KPS + KT + vseg*8);

    for (int t = 0; t < NTS; ++t) {
        __syncthreads();
        bf16x8 k0c = k0b, k1c = k1b, vc_ = vb_;
        if (t + 2 < NTS) {               // issue loads for tile t+2
            int kt = (t + 2) * KT;
            k0c = *(const bf16x8*)(Kb + (size_t)(kt + r0)*32 + 8*h0);
            k1c = *(const bf16x8*)(Kb + (size_t)(kt + r1)*32 + 8*h1);
            vc_ = *(const bf16x8*)(Vb + (size_t)vd*HW + s*KPS + kt + vseg*8);
        }

        const ushort* kr = &Ks[s][t & 1][0] + koff;
        const ushort* vr = &Vs[s][t & 1][0] + voff;
        unsigned int pe00 = 0, pe01 = 0, pe10 = 0, pe11 = 0;
        #pragma unroll
        for (int kb = 0; kb < 4; ++kb) {
            bf16x8 kfrag = *(const bf16x8*)(kr + kb*512);
            // q-tile 0
            f32x4 sA = __builtin_amdgcn_mfma_f32_16x16x32_bf16(kfrag, qhi0, zero4, 0, 0, 0);
            sA = __builtin_amdgcn_mfma_f32_16x16x32_bf16(kfrag, qlo0, sA, 0, 0, 0);
            float a0 = __builtin_amdgcn_exp2f(sA.x);
            float a1 = __builtin_amdgcn_exp2f(sA.y);
            float a2 = __builtin_amdgcn_exp2f(sA.z);
            float a3 = __builtin_amdgcn_exp2f(sA.w);
            unsigned int alo = cvt_pk_bf16(a0, a1);
            unsigned int ahi = cvt_pk_bf16(a2, a3);
            // q-tile 1
            f32x4 sB = __builtin_amdgcn_mfma_f32_16x16x32_bf16(kfrag, qhi1, zero4, 0, 0, 0);
            sB = __builtin_amdgcn_mfma_f32_16x16x32_bf16(kfrag, qlo1, sB, 0, 0, 0);
            float b0 = __builtin_amdgcn_exp2f(sB.x);
            float b1 = __builtin_amdgcn_exp2f(sB.y);
            float b2 = __builtin_amdgcn_exp2f(sB.z);
            float b3 = __builtin_amdgcn_exp2f(sB.w);
            unsigned int blo = cvt_pk_bf16(b0, b1);
            unsigned int bhi = cvt_pk_bf16(b2, b3);

            if ((kb & 1) == 0) { pe00 = alo; pe01 = ahi; pe10 = blo; pe11 = bhi; }
            else {
                uint2v vE = *(const uint2v*)(vr + (kb-1)*16);
                uint2v vO = *(const uint2v*)(vr + kb*16);
                union { unsigned int uu[4]; bf16x8 h; } pa, vv;
                vv.uu[0] = vE.x; vv.uu[1] = vE.y; vv.uu[2] = vO.x; vv.uu[3] = vO.y;
                pa.uu[0] = pe00; pa.uu[1] = pe01; pa.uu[2] = alo; pa.uu[3] = ahi;
                oacc0  = __builtin_amdgcn_mfma_f32_16x16x32_bf16(pa.h, vv.h,   oacc0,  0, 0, 0);
                oaccL0 = __builtin_amdgcn_mfma_f32_16x16x32_bf16(pa.h, ones.h, oaccL0, 0, 0, 0);
                pa.uu[0] = pe10; pa.uu[1] = pe11; pa.uu[2] = blo; pa.uu[3] = bhi;
                oacc1  = __builtin_amdgcn_mfma_f32_16x16x32_bf16(pa.h, vv.h,   oacc1,  0, 0, 0);
                oaccL1 = __builtin_amdgcn_mfma_f32_16x16x32_bf16(pa.h, ones.h, oaccL1, 0, 0, 0);
            }
        }

        if (t + 1 < NTS) {               // write in-flight tile -> other buf
            int nb = (t + 1) & 1;
            *(bf16x8*)(&Ks[s][nb][0] + r0*32 + s0) = k0b;
            *(bf16x8*)(&Ks[s][nb][0] + r1*32 + s1) = k1b;
            *(bf16x8*)(&Vs[s][nb][0] + vd*72 + vseg*8) = vb_;
            k0b = k0c; k1b = k1c; vb_ = vc_;
        }
    }

    // merge splits 1..3 -> split 0, reusing Ks LDS (staging dead now)
    // entry per (split-1, u, qtile, lane): 8 floats = oacc.xyzw | oaccL.xyzw
    __syncthreads();
    float* mrgF = (float*)&Ks[0][0][0];   // [3][2][2][64][8] = 24KB
    if (s > 0) {
        float* m0 = mrgF + (((((s-1)*2 + u)*2 + 0)*64 + lane)*8);
        m0[0] = oacc0.x;  m0[1] = oacc0.y;  m0[2] = oacc0.z;  m0[3] = oacc0.w;
        m0[4] = oaccL0.x; m0[5] = oaccL0.y; m0[6] = oaccL0.z; m0[7] = oaccL0.w;
        float* m1 = mrgF + (((((s-1)*2 + u)*2 + 1)*64 + lane)*8);
        m1[0] = oacc1.x;  m1[1] = oacc1.y;  m1[2] = oacc1.z;  m1[3] = oacc1.w;
        m1[4] = oaccL1.x; m1[5] = oaccL1.y; m1[6] = oaccL1.z; m1[7] = oaccL1.w;
    }
    __syncthreads();
    if (s == 0) {
        #pragma unroll
        for (int sp = 0; sp < 3; ++sp) {
            const float* m0 = mrgF + ((((sp*2 + u)*2 + 0)*64 + lane)*8);
            oacc0.x  += m0[0]; oacc0.y  += m0[1]; oacc0.z  += m0[2]; oacc0.w  += m0[3];
            oaccL0.x += m0[4]; oaccL0.y += m0[5]; oaccL0.z += m0[6]; oaccL0.w += m0[7];
            const float* m1 = mrgF + ((((sp*2 + u)*2 + 1)*64 + lane)*8);
            oacc1.x  += m1[0]; oacc1.y  += m1[1]; oacc1.z  += m1[2]; oacc1.w  += m1[3];
            oaccL1.x += m1[4]; oaccL1.y += m1[5]; oaccL1.z += m1[6]; oaccL1.w += m1[7];
        }
        int b = bh >> 2, h = bh & 3;
        float* Ob0 = O + ((size_t)b*HW + q0 + (u*2 + 0)*16)*NC + h*DH;
        float* Ob1 = O + ((size_t)b*HW + q0 + (u*2 + 1)*16)*NC + h*DH;
        #pragma unroll
        for (int r = 0; r < 4; ++r) {
            float ov0 = (r==0? oacc0.x  : r==1? oacc0.y  : r==2? oacc0.z  : oacc0.w);
            float lv0 = (r==0? oaccL0.x : r==1? oaccL0.y : r==2? oaccL0.z : oaccL0.w);
            Ob0[(4*g + r)*NC + qc] = ov0 / lv0;
            float ov1 = (r==0? oacc1.x  : r==1? oacc1.y  : r==2? oacc1.z  : oacc1.w);
            float lv1 = (r==0? oaccL1.x : r==1? oaccL1.y : r==2? oaccL1.z : oaccL1.w);
            Ob1[(4*g + r)*NC + qc] = ov1 / lv1;
        }
    }
}

// ---------------------------------------------------------------------------
// Kernel C: proj as double-bf16 MFMA GEMM (round-14 verbatim).
// ---------------------------------------------------------------------------
__global__ __launch_bounds__(256) void proj_kernel(
    const float* __restrict__ O, const ushort* __restrict__ Wp,
    const float* __restrict__ proj_b, float* __restrict__ y)
{
    __shared__ alignas(16) float  of[64*20];     // [c][16 px + 4 pad]
    __shared__ alignas(16) ushort frag[4*16*32]; // [ct][px][32 swz]
    __shared__ alignas(16) float  ys[64][20];    // [c][px]

    int blk = blockIdx.x;                // 512
    int b   = blk & 1;
    int px0 = (blk >> 1) * 16;
    int tid = threadIdx.x;
    int w   = tid >> 6;
    int lane = tid & 63;
    int g   = lane >> 4;
    int n   = lane & 15;

    {
        int px = tid >> 4, c4 = tid & 15;
        float4 v = *(const float4*)(O + ((size_t)(b*HW + px0 + px))*NC + c4*4);
        of[(c4*4+0)*20 + px] = v.x;
        of[(c4*4+1)*20 + px] = v.y;
        of[(c4*4+2)*20 + px] = v.z;
        of[(c4*4+3)*20 + px] = v.w;
    }
    __syncthreads();

    if (tid < 64) {
        int ct = tid >> 4, px = tid & 15;
        int swz = (px & 3) ^ ((px >> 2) & 3);
        union { ushort us[8]; bf16x8 v; } g0, g1, g2, g3;
        #pragma unroll
        for (int i = 0; i < 8; ++i) {
            float v  = of[(ct*16 + i)*20 + px];
            unsigned short hb = bf16_bits(v);
            g0.us[i] = hb;
            g2.us[i] = bf16_bits(v - bits_to_f(hb));
            float v2 = of[(ct*16 + 8 + i)*20 + px];
            unsigned short hb2 = bf16_bits(v2);
            g1.us[i] = hb2;
            g3.us[i] = bf16_bits(v2 - bits_to_f(hb2));
        }
        ushort* fb = frag + (ct*16 + px)*32;
        *(bf16x8*)(fb + ((0 ^ swz)*8)) = g0.v;
        *(bf16x8*)(fb + ((1 ^ swz)*8)) = g1.v;
        *(bf16x8*)(fb + ((2 ^ swz)*8)) = g2.v;
        *(bf16x8*)(fb + ((3 ^ swz)*8)) = g3.v;
    }
    __syncthreads();

    f32x4 acc = {0.f, 0.f, 0.f, 0.f};
    int px  = n;
    int swz = (px & 3) ^ ((px >> 2) & 3);
    const ushort* af_base = frag + px*32 + (g ^ swz)*8;
    #pragma unroll
    for (int ct = 0; ct < 4; ++ct) {
        bf16x8 af = *(const bf16x8*)(af_base + ct*512);
        const ushort* wb = Wp + ((size_t)(w*4 + ct)*2)*256 + n*16 + (g&1)*8;
        bf16x8 bh = *(const bf16x8*)(wb);
        bf16x8 bl = *(const bf16x8*)(wb + 256);
        acc = __builtin_amdgcn_mfma_f32_16x16x32_bf16(af, bh, acc, 0, 0, 0);
        acc = __builtin_amdgcn_mfma_f32_16x16x32_bf16(af, bl, acc, 0, 0, 0);
    }
    float bias = proj_b[w*16 + n];
    ys[w*16 + n][4*g+0] = acc.x + bias;
    ys[w*16 + n][4*g+1] = acc.y + bias;
    ys[w*16 + n][4*g+2] = acc.z + bias;
    ys[w*16 + n][4*g+3] = acc.w + bias;
    __syncthreads();

    {
        int row = tid >> 2, seg = tid & 3;
        float4 v;
        v.x = ys[row][seg*4+0]; v.y = ys[row][seg*4+1];
        v.z = ys[row][seg*4+2]; v.w = ys[row][seg*4+3];
        *(float4*)(y + ((size_t)(b*NC + row))*HW + px0 + seg*4) = v;
    }
}

// ---------------------------------------------------------------------------
extern "C" void kernel_launch(void* const* d_in, const int* in_sizes, int n_in,
                              void* d_out, int out_size, void* d_ws, size_t ws_size,
                              hipStream_t stream)
{
    const float* x      = (const float*)d_in[0];
    const float* illu   = (const float*)d_in[1];
    const float* qkv_w  = (const float*)d_in[2];
    const float* qkv_b  = (const float*)d_in[3];
    const float* illu_w = (const float*)d_in[4];
    const float* illu_b = (const float*)d_in[5];
    const float* proj_w = (const float*)d_in[6];
    const float* proj_b = (const float*)d_in[7];
    float* out = (float*)d_out;

    ushort* Qx   = (ushort*)d_ws;                     // 2MB (hi|lo)
    ushort* Kx   = Qx + (size_t)NBH*HW*32;            // 2MB (hi|lo)
    ushort* Vt   = Kx + (size_t)NBH*HW*32;            // 1MB [bh][d][key]
    float*  O    = (float*)(Vt + (size_t)NBH*HW*DH);  // 2MB fp32 [b][p][64]
    ushort* Wt   = (ushort*)(O + (size_t)NB*HW*NC);   // 96KB
    float*  Bias = (float*)(Wt + 49152);              // 768B
    ushort* Wp   = (ushort*)(Bias + 192);             // 16KB

    hipLaunchKernelGGL(wprep_kernel, dim3(225), dim3(256), 0, stream,
                       qkv_w, qkv_b, illu_w, illu_b, proj_w, Wt, Bias, Wp);
    hipLaunchKernelGGL(qkv_kernel, dim3(512), dim3(256), 0, stream,
                       x, illu, Wt, Bias, Qx, Kx, Vt);
    hipLaunchKernelGGL(attn_kernel, dim3(512), dim3(512), 0, stream,
                       Qx, Kx, Vt, O);
    hipLaunchKernelGGL(proj_kernel, dim3(512), dim3(256), 0, stream,
                       O, Wp, proj_b, out);
}